// Round 5
// baseline (336.952 us; speedup 1.0000x reference)
//
#include <hip/hip_runtime.h>
#include <hip/hip_bf16.h>

typedef unsigned int u32;
typedef unsigned short u16;

static constexpr int Cn = 96;
static constexpr int HWn = 65536;

typedef __attribute__((ext_vector_type(8))) short bf16x8;
typedef __attribute__((ext_vector_type(4))) float f32x4;

__device__ __forceinline__ float bf2f(u16 u) {
    union { u32 i; float f; } z; z.i = ((u32)u) << 16; return z.f;
}
__device__ __forceinline__ u16 f2bf(float f) {
    __hip_bfloat16 h = __float2bfloat16(f);
    return *reinterpret_cast<u16*>(&h);
}
__device__ __forceinline__ u32 pack2(float a, float b) {
    return ((u32)f2bf(b) << 16) | (u32)f2bf(a);
}
__device__ __forceinline__ float lo2f(u32 u) {
    union { u32 i; float f; } z; z.i = u << 16; return z.f;
}
__device__ __forceinline__ float hi2f(u32 u) {
    union { u32 i; float f; } z; z.i = u & 0xffff0000u; return z.f;
}
__device__ __forceinline__ float sq2bf(u32 a) {
    union { u32 i; float f; } al, ah;
    al.i = a << 16; ah.i = a & 0xffff0000u;
    return fmaf(al.f, al.f, ah.f * ah.f);
}

// Swizzled LDS offset (u16 units) for transposed X tile: [px 0..127][ic 0..95]
__device__ __forceinline__ int xoff(int px, int icb) {
    return px * 128 + (((icb ^ (px & 7) ^ ((px >> 3) & 7))) << 3);
}

// Split conv1x1 weights into bf16 hi/lo, layout [sec*96+oc][ic]
__global__ __launch_bounds__(256) void k_prep_w(
    const float* __restrict__ wq, const float* __restrict__ wkv,
    u16* __restrict__ whi, u16* __restrict__ wlo)
{
    const int i = blockIdx.x * 256 + threadIdx.x;
    if (i >= 288 * 96) return;
    const int row = i / 96, ic = i % 96;
    const float w = (row < 96) ? wq[row * 96 + ic] : wkv[(row - 96) * 96 + ic];
    const u16 h = f2bf(w);
    whi[i] = h;
    wlo[i] = f2bf(w - bf2f(h));
}

// K1: conv1x1 via MFMA. grid (512 px-tiles, 3 sec {q,kv0,kv1}, 4 b), 256 thr.
// 32 KB LDS single X buffer; stage Xhi -> (Whi+Wlo)*Xhi, restage Xlo -> Whi*Xlo.
__global__ __launch_bounds__(256, 4) void k_conv_mfma(
    const float* __restrict__ ff, const float* __restrict__ x,
    const u16* __restrict__ whi, const u16* __restrict__ wlo,
    u16* __restrict__ qpre, u16* __restrict__ kvpre)
{
    const int b = blockIdx.z, sec = blockIdx.y;
    const int px0 = blockIdx.x * 128;
    const int tid = threadIdx.x;

    __shared__ __align__(16) u16 xs[16384];     // 32 KB

    const float* src = (sec == 0 ? ff : x) + (size_t)b * 96 * HWn;
    const u16* wh = whi + sec * 96 * 96;
    const u16* wl = wlo + sec * 96 * 96;
    u16* dst = (sec == 0) ? (qpre + (size_t)b * 96 * HWn)
                          : (kvpre + (size_t)b * 192 * HWn + (size_t)(sec - 1) * 96 * HWn);

    // staging map: ic pair = (p*32 + (tid>>4)*2, +1), px run of 8 at (tid&15)*8
    const int icq = (tid >> 4) * 2;
    const int pxs = (tid & 15) * 8;

    const int lane = tid & 63;
    const int wv = tid >> 6;
    const int oc0 = (wv >> 1) * 48;
    const int pxw = (wv & 1) * 64;
    const int lr = lane & 15, lg = lane >> 4;

    f32x4 acc[3][4];
    #pragma unroll
    for (int m = 0; m < 3; ++m)
        #pragma unroll
        for (int n = 0; n < 4; ++n)
            acc[m][n] = (f32x4){0.f, 0.f, 0.f, 0.f};

    #pragma unroll 1
    for (int phase = 0; phase < 2; ++phase) {
        // ---- stage (phase 0: hi parts; phase 1: lo parts) ----
        #pragma unroll 1
        for (int p = 0; p < 3; ++p) {
            const int ic = p * 32 + icq;
            const float* rp0 = src + (size_t)ic * HWn + px0 + pxs;
            const float* rp1 = rp0 + HWn;
            const float4 a0 = *reinterpret_cast<const float4*>(rp0);
            const float4 a1 = *reinterpret_cast<const float4*>(rp0 + 4);
            const float4 b0 = *reinterpret_cast<const float4*>(rp1);
            const float4 b1 = *reinterpret_cast<const float4*>(rp1 + 4);
            const int icb = ic >> 3, icl = ic & 7;
            float e0[8] = {a0.x, a0.y, a0.z, a0.w, a1.x, a1.y, a1.z, a1.w};
            float e1[8] = {b0.x, b0.y, b0.z, b0.w, b1.x, b1.y, b1.z, b1.w};
            #pragma unroll
            for (int j = 0; j < 8; ++j) {
                float v0 = e0[j], v1 = e1[j];
                if (phase) {                     // lo residual
                    v0 = v0 - bf2f(f2bf(v0));
                    v1 = v1 - bf2f(f2bf(v1));
                }
                const int o = xoff(pxs + j, icb) + icl;   // even
                *reinterpret_cast<u32*>(&xs[o]) = pack2(v0, v1);
            }
        }
        __syncthreads();

        // ---- compute ----
        #pragma unroll 1
        for (int kt = 0; kt < 3; ++kt) {
            const int kb = kt * 32;
            bf16x8 B[4];
            #pragma unroll
            for (int n = 0; n < 4; ++n)
                B[n] = *(const bf16x8*)(xs + xoff(pxw + n * 16 + lr, (kb >> 3) + lg));
            bf16x8 A[3];
            #pragma unroll
            for (int m = 0; m < 3; ++m)
                A[m] = *(const bf16x8*)(wh + (oc0 + m * 16 + lr) * 96 + kb + lg * 8);
            #pragma unroll
            for (int m = 0; m < 3; ++m)
                #pragma unroll
                for (int n = 0; n < 4; ++n)
                    acc[m][n] = __builtin_amdgcn_mfma_f32_16x16x32_bf16(A[m], B[n], acc[m][n], 0, 0, 0);
            if (phase == 0) {                    // Wlo * Xhi reuses B
                #pragma unroll
                for (int m = 0; m < 3; ++m)
                    A[m] = *(const bf16x8*)(wl + (oc0 + m * 16 + lr) * 96 + kb + lg * 8);
                #pragma unroll
                for (int m = 0; m < 3; ++m)
                    #pragma unroll
                    for (int n = 0; n < 4; ++n)
                        acc[m][n] = __builtin_amdgcn_mfma_f32_16x16x32_bf16(A[m], B[n], acc[m][n], 0, 0, 0);
            }
        }
        if (phase == 0) __syncthreads();         // before overwriting xs
    }

    #pragma unroll
    for (int m = 0; m < 3; ++m) {
        #pragma unroll
        for (int i = 0; i < 4; ++i) {
            const int oc = oc0 + m * 16 + lg * 4 + i;
            u16* drow = dst + (size_t)oc * HWn + px0;
            #pragma unroll
            for (int n = 0; n < 4; ++n)
                drow[pxw + n * 16 + lr] = f2bf(acc[m][n][i]);
        }
    }
}

// K2: fused depthwise 3x3 + reductions. 128-px half-row tiles, 512 thr,
// LDS 52 KB. Horizontal halo via __shfl; S via MFMA.
__global__ __launch_bounds__(512) void k_dw_fused(
    const u16* __restrict__ qpre, const u16* __restrict__ kvpre,
    const float* __restrict__ wqdw, const float* __restrict__ wkvdw,
    u16* __restrict__ vout, float* __restrict__ ssq, float* __restrict__ Sg)
{
    const int bid = blockIdx.x;                  // 0..2047
    const int wg = (bid & 7) * 256 + (bid >> 3);
    const int b = wg >> 9;
    const int rem = wg & 511;
    const int y = rem >> 1;
    const int tx = (rem & 1) * 128;
    const int tid = threadIdx.x;
    const int lane = tid & 63;
    const int chunk = tid & 15;
    const int x0l = chunk * 8;
    const int xg = tx + x0l;

    __shared__ __align__(16) u16 qs[96][136];
    __shared__ __align__(16) u16 ks[96][136];

    #pragma unroll 1
    for (int it = 0; it < 9; ++it) {
        const int p = it * 32 + (tid >> 4);
        const u16* src; const float* wp; int c;
        if (p < 96)       { c = p;       src = qpre  + ((size_t)(b * 96 + c)) * HWn;       wp = wqdw  + c * 9; }
        else if (p < 192) { c = p - 96;  src = kvpre + ((size_t)(b * 192 + c)) * HWn;      wp = wkvdw + c * 9; }
        else              { c = p - 192; src = kvpre + ((size_t)(b * 192 + 96 + c)) * HWn; wp = wkvdw + (96 + c) * 9; }

        float a0 = 0.f, a1 = 0.f, a2 = 0.f, a3 = 0.f, a4 = 0.f, a5 = 0.f, a6 = 0.f, a7 = 0.f;

        #pragma unroll
        for (int r = 0; r < 3; ++r) {
            const int ry = y + r - 1;
            if ((unsigned)ry < 256u) {
                const u16* row = src + ry * 256 + xg;
                const uint4 m = *reinterpret_cast<const uint4*>(row);
                const float v1 = lo2f(m.x), v2 = hi2f(m.x);
                const float v3 = lo2f(m.y), v4 = hi2f(m.y);
                const float v5 = lo2f(m.z), v6 = hi2f(m.z);
                const float v7 = lo2f(m.w), v8 = hi2f(m.w);
                const float lv = __shfl(v8, (lane - 1) & 63);
                const float rv = __shfl(v1, (lane + 1) & 63);
                const float v0 = (chunk == 0)  ? ((xg > 0)       ? bf2f(row[-1]) : 0.f) : lv;
                const float v9 = (chunk == 15) ? ((xg + 8 < 256) ? bf2f(row[8])  : 0.f) : rv;
                const float w0 = wp[r * 3 + 0], w1 = wp[r * 3 + 1], w2 = wp[r * 3 + 2];
                a0 = fmaf(w0, v0, fmaf(w1, v1, fmaf(w2, v2, a0)));
                a1 = fmaf(w0, v1, fmaf(w1, v2, fmaf(w2, v3, a1)));
                a2 = fmaf(w0, v2, fmaf(w1, v3, fmaf(w2, v4, a2)));
                a3 = fmaf(w0, v3, fmaf(w1, v4, fmaf(w2, v5, a3)));
                a4 = fmaf(w0, v4, fmaf(w1, v5, fmaf(w2, v6, a4)));
                a5 = fmaf(w0, v5, fmaf(w1, v6, fmaf(w2, v7, a5)));
                a6 = fmaf(w0, v6, fmaf(w1, v7, fmaf(w2, v8, a6)));
                a7 = fmaf(w0, v7, fmaf(w1, v8, fmaf(w2, v9, a7)));
            }
        }

        const uint4 o = make_uint4(pack2(a0, a1), pack2(a2, a3), pack2(a4, a5), pack2(a6, a7));
        if (p < 96) {
            *reinterpret_cast<uint4*>(&qs[c][x0l]) = o;
        } else if (p < 192) {
            *reinterpret_cast<uint4*>(&ks[c][x0l]) = o;
        } else {
            *reinterpret_cast<uint4*>(vout + ((size_t)(b * 96 + c)) * HWn + y * 256 + xg) = o;
        }
    }
    __syncthreads();

    if (tid < 384) {
        const int half = tid >= 192;
        const int r = tid - half * 192;
        const uint4* rr = reinterpret_cast<const uint4*>(
            (r < 96 ? &qs[r][0] : &ks[r - 96][0]) + half * 64);
        float s = 0.f;
        #pragma unroll
        for (int pch = 0; pch < 8; ++pch) {
            const uint4 a = rr[pch];
            s += sq2bf(a.x) + sq2bf(a.y) + sq2bf(a.z) + sq2bf(a.w);
        }
        atomicAdd(ssq + b * 192 + r, s);
    }

    {
        const int w = tid >> 6;
        const int h = w & 3, mt = w >> 2;
        const int lr2 = lane & 15, lg2 = lane >> 4;
        const int ar = h * 24 + min(mt * 16 + lr2, 23);
        f32x4 acc2[2];
        acc2[0] = (f32x4){0.f, 0.f, 0.f, 0.f};
        acc2[1] = (f32x4){0.f, 0.f, 0.f, 0.f};
        #pragma unroll
        for (int ks4 = 0; ks4 < 4; ++ks4) {
            const bf16x8 A = *(const bf16x8*)(&qs[ar][ks4 * 32 + lg2 * 8]);
            #pragma unroll
            for (int nt = 0; nt < 2; ++nt) {
                const int bc = h * 24 + min(nt * 16 + lr2, 23);
                const bf16x8 B = *(const bf16x8*)(&ks[bc][ks4 * 32 + lg2 * 8]);
                acc2[nt] = __builtin_amdgcn_mfma_f32_16x16x32_bf16(A, B, acc2[nt], 0, 0, 0);
            }
        }
        #pragma unroll
        for (int nt = 0; nt < 2; ++nt) {
            const int col = nt * 16 + lr2;
            #pragma unroll
            for (int reg = 0; reg < 4; ++reg) {
                const int row24 = mt * 16 + lg2 * 4 + reg;
                if (row24 < 24 && col < 24)
                    atomicAdd(Sg + b * 2304 + h * 576 + row24 * 24 + col, acc2[nt][reg]);
            }
        }
    }
}

// K3: normalize, softmax, fold w_out with block-diag attn -> Mhi/Mlo [oc][dg] bf16
__global__ __launch_bounds__(256) void k_attn_fold(
    const float* __restrict__ ssq, const float* __restrict__ S,
    const float* __restrict__ temp, const float* __restrict__ w_out,
    u16* __restrict__ mhi, u16* __restrict__ mlo)
{
    const int b = blockIdx.x;
    const int tid = threadIdx.x;
    __shared__ float rq[96], rk[96], att[2304];

    if (tid < 96) {
        rq[tid] = 1.f / fmaxf(sqrtf(ssq[b * 192 + tid]), 1e-12f);
    } else if (tid < 192) {
        const int c = tid - 96;
        rk[c] = 1.f / fmaxf(sqrtf(ssq[b * 192 + 96 + c]), 1e-12f);
    }
    __syncthreads();

    if (tid < 96) {
        const int h = tid / 24, i = tid % 24;
        const float tmp = temp[h];
        const float rqi = rq[h * 24 + i];
        float l[24];
        float m = -1e30f;
        #pragma unroll
        for (int j = 0; j < 24; ++j) {
            l[j] = S[b * 2304 + (h * 24 + i) * 24 + j] * rqi * rk[h * 24 + j] * tmp;
            m = fmaxf(m, l[j]);
        }
        float ssum = 0.f;
        #pragma unroll
        for (int j = 0; j < 24; ++j) { l[j] = expf(l[j] - m); ssum += l[j]; }
        const float inv = 1.f / ssum;
        #pragma unroll
        for (int j = 0; j < 24; ++j) att[(h * 24 + i) * 24 + j] = l[j] * inv;
    }
    __syncthreads();

    for (int k = 0; k < 36; ++k) {
        const int id = k * 256 + tid;
        const int dg = id / 96, oc = id % 96;
        const int h = dg / 24, d24 = dg % 24;
        float s = 0.f;
        #pragma unroll
        for (int i = 0; i < 24; ++i) {
            s += w_out[oc * 96 + h * 24 + i] * att[(h * 24 + i) * 24 + d24];
        }
        const u16 hh = f2bf(s);
        mhi[b * 9216 + oc * 96 + dg] = hh;
        mlo[b * 9216 + oc * 96 + dg] = f2bf(s - bf2f(hh));
    }
}

// K4: out = M @ v via MFMA. grid (512 px-tiles, 4 b), 256 thr.
__global__ __launch_bounds__(256, 4) void k_out_mfma(
    const u16* __restrict__ v, const u16* __restrict__ mhi, const u16* __restrict__ mlo,
    float* __restrict__ out)
{
    const int b = blockIdx.y;
    const int px0 = blockIdx.x * 128;
    const int tid = threadIdx.x;
    __shared__ __align__(16) u16 xt[16384];

    const u16* vb = v + (size_t)b * 96 * HWn;
    const u16* mh = mhi + b * 9216;
    const u16* ml = mlo + b * 9216;

    const int icq = (tid >> 4) * 2;
    const int pxs = (tid & 15) * 8;
    #pragma unroll 1
    for (int p = 0; p < 3; ++p) {
        const int dg = p * 32 + icq;
        const uint4 u0 = *reinterpret_cast<const uint4*>(vb + (size_t)dg * HWn + px0 + pxs);
        const uint4 u1 = *reinterpret_cast<const uint4*>(vb + (size_t)(dg + 1) * HWn + px0 + pxs);
        const u32 w0[4] = {u0.x, u0.y, u0.z, u0.w};
        const u32 w1[4] = {u1.x, u1.y, u1.z, u1.w};
        const int icb = dg >> 3, icl = dg & 7;
        #pragma unroll
        for (int j = 0; j < 8; ++j) {
            const u32 lo = (w0[j >> 1] >> ((j & 1) * 16)) & 0xffffu;
            const u32 hi = (w1[j >> 1] >> ((j & 1) * 16)) & 0xffffu;
            const int o = xoff(pxs + j, icb) + icl;      // even
            *reinterpret_cast<u32*>(&xt[o]) = (hi << 16) | lo;
        }
    }
    __syncthreads();

    const int lane = tid & 63;
    const int wv = tid >> 6;
    const int oc0 = (wv >> 1) * 48;
    const int pxw = (wv & 1) * 64;
    const int lr = lane & 15, lg = lane >> 4;

    f32x4 acc[3][4];
    #pragma unroll
    for (int m = 0; m < 3; ++m)
        #pragma unroll
        for (int n = 0; n < 4; ++n)
            acc[m][n] = (f32x4){0.f, 0.f, 0.f, 0.f};

    #pragma unroll 1
    for (int kt = 0; kt < 3; ++kt) {
        const int kb = kt * 32;
        bf16x8 B[4];
        #pragma unroll
        for (int n = 0; n < 4; ++n)
            B[n] = *(const bf16x8*)(xt + xoff(pxw + n * 16 + lr, (kb >> 3) + lg));
        bf16x8 A[3];
        #pragma unroll
        for (int m = 0; m < 3; ++m)
            A[m] = *(const bf16x8*)(mh + (oc0 + m * 16 + lr) * 96 + kb + lg * 8);
        #pragma unroll
        for (int m = 0; m < 3; ++m)
            #pragma unroll
            for (int n = 0; n < 4; ++n)
                acc[m][n] = __builtin_amdgcn_mfma_f32_16x16x32_bf16(A[m], B[n], acc[m][n], 0, 0, 0);
        #pragma unroll
        for (int m = 0; m < 3; ++m)
            A[m] = *(const bf16x8*)(ml + (oc0 + m * 16 + lr) * 96 + kb + lg * 8);
        #pragma unroll
        for (int m = 0; m < 3; ++m)
            #pragma unroll
            for (int n = 0; n < 4; ++n)
                acc[m][n] = __builtin_amdgcn_mfma_f32_16x16x32_bf16(A[m], B[n], acc[m][n], 0, 0, 0);
    }

    #pragma unroll
    for (int m = 0; m < 3; ++m) {
        #pragma unroll
        for (int i = 0; i < 4; ++i) {
            const int oc = oc0 + m * 16 + lg * 4 + i;
            float* drow = out + ((size_t)(b * 96 + oc)) * HWn + px0;
            #pragma unroll
            for (int n = 0; n < 4; ++n)
                drow[pxw + n * 16 + lr] = acc[m][n][i];
        }
    }
}

extern "C" void kernel_launch(void* const* d_in, const int* in_sizes, int n_in,
                              void* d_out, int out_size, void* d_ws, size_t ws_size,
                              hipStream_t stream) {
    (void)in_sizes; (void)n_in; (void)out_size; (void)ws_size;
    const float* x      = (const float*)d_in[0];
    const float* ff     = (const float*)d_in[1];
    const float* w_q    = (const float*)d_in[2];
    const float* w_kv   = (const float*)d_in[3];
    const float* w_q_dw = (const float*)d_in[4];
    const float* w_kv_dw= (const float*)d_in[5];
    const float* w_out  = (const float*)d_in[6];
    const float* temp   = (const float*)d_in[7];
    float* out = (float*)d_out;

    char* ws = (char*)d_ws;
    u16* qpre   = (u16*)(ws);                      //  50,331,648 B
    u16* kvpre  = (u16*)(ws + 50331648);           // 100,663,296 B
    u16* vbuf   = (u16*)(ws + 150994944);          //  50,331,648 B
    float* ssq  = (float*)(ws + 201326592);        //       3,072 B
    float* S    = (float*)(ws + 201329664);        //      36,864 B
    u16* whi    = (u16*)(ws + 201366528);          //      55,296 B
    u16* wlo    = (u16*)(ws + 201421824);          //      55,296 B
    u16* mhi    = (u16*)(ws + 201477120);          //      73,728 B
    u16* mlo    = (u16*)(ws + 201550848);          //      73,728 B

    hipMemsetAsync(ssq, 0, 3072 + 36864, stream);

    k_prep_w<<<108, 256, 0, stream>>>(w_q, w_kv, whi, wlo);
    k_conv_mfma<<<dim3(512, 3, 4), 256, 0, stream>>>(ff, x, whi, wlo, qpre, kvpre);
    k_dw_fused<<<dim3(2048), 512, 0, stream>>>(qpre, kvpre, w_q_dw, w_kv_dw, vbuf, ssq, S);
    k_attn_fold<<<4, 256, 0, stream>>>(ssq, S, temp, w_out, mhi, mlo);
    k_out_mfma<<<dim3(512, 4), 256, 0, stream>>>(vbuf, mhi, mlo, out);
}

// Round 6
// 275.408 us; speedup vs baseline: 1.2235x; 1.2235x over previous
//
#include <hip/hip_runtime.h>
#include <hip/hip_bf16.h>
#include <hip/hip_fp16.h>

typedef unsigned int u32;
typedef unsigned short u16;
typedef _Float16 f16;

static constexpr int HWn = 65536;

typedef __attribute__((ext_vector_type(8))) f16 f16x8;
typedef __attribute__((ext_vector_type(4))) float f32x4;

__device__ __forceinline__ float h2f(u16 u) {
    union { u16 s; f16 h; } z; z.s = u; return (float)z.h;
}
__device__ __forceinline__ u16 f2h(float f) {
    union { u16 s; f16 h; } z; z.h = (f16)f; return z.s;
}
__device__ __forceinline__ u32 pack2h(float a, float b) {
    union { u32 i; f16 h[2]; } z; z.h[0] = (f16)a; z.h[1] = (f16)b; return z.i;
}
__device__ __forceinline__ float hlo(u32 u) {
    union { u32 i; f16 h[2]; } z; z.i = u; return (float)z.h[0];
}
__device__ __forceinline__ float hhi(u32 u) {
    union { u32 i; f16 h[2]; } z; z.i = u; return (float)z.h[1];
}
__device__ __forceinline__ float sq2h(u32 a) {
    const float l = hlo(a), h = hhi(a);
    return fmaf(l, l, h * h);
}

// Swizzled LDS offset (u16 units) for transposed X tile: [px 0..127][ic 0..95],
// pitch 128 u16/px; granule 8; proven ~2-way banks for staging writes + b128 reads.
__device__ __forceinline__ int xoff(int px, int icb) {
    return px * 128 + (((icb ^ (px & 7) ^ ((px >> 3) & 7))) << 3);
}

// Convert conv1x1 weights to f16, layout [row 0..287][ic 0..95]
__global__ __launch_bounds__(256) void k_prep_w(
    const float* __restrict__ wq, const float* __restrict__ wkv,
    u16* __restrict__ wf)
{
    const int i = blockIdx.x * 256 + threadIdx.x;
    if (i >= 288 * 96) return;
    const int row = i / 96, ic = i % 96;
    const float w = (row < 96) ? wq[row * 96 + ic] : wkv[(row - 96) * 96 + ic];
    wf[i] = f2h(w);
}

// K1: conv1x1 via f16 MFMA. grid (512 px-tiles, 2 sec {q, kv}, 4 b), 256 thr.
// Single 32 KB f16 X buffer, staged once; sec==1 runs two weight passes (kv0,kv1).
__global__ __launch_bounds__(256, 5) void k_conv_mfma(
    const float* __restrict__ ff, const float* __restrict__ x,
    const u16* __restrict__ wf,
    u16* __restrict__ qpre, u16* __restrict__ kvpre)
{
    const int b = blockIdx.z, sec = blockIdx.y;
    const int px0 = blockIdx.x * 128;
    const int tid = threadIdx.x;

    __shared__ __align__(16) u16 xs[16384];     // 32 KB, f16 bits

    const float* src = (sec == 0 ? ff : x) + (size_t)b * 96 * HWn;

    // stage: ic pair = (p*32 + (tid>>4)*2, +1), px run of 8 at (tid&15)*8
    const int icq = (tid >> 4) * 2;
    const int pxs = (tid & 15) * 8;
    #pragma unroll 1
    for (int p = 0; p < 3; ++p) {
        const int ic = p * 32 + icq;
        const float* rp0 = src + (size_t)ic * HWn + px0 + pxs;
        const float* rp1 = rp0 + HWn;
        const float4 a0 = *reinterpret_cast<const float4*>(rp0);
        const float4 a1 = *reinterpret_cast<const float4*>(rp0 + 4);
        const float4 b0 = *reinterpret_cast<const float4*>(rp1);
        const float4 b1 = *reinterpret_cast<const float4*>(rp1 + 4);
        const int icb = ic >> 3, icl = ic & 7;
        const float e0[8] = {a0.x, a0.y, a0.z, a0.w, a1.x, a1.y, a1.z, a1.w};
        const float e1[8] = {b0.x, b0.y, b0.z, b0.w, b1.x, b1.y, b1.z, b1.w};
        #pragma unroll
        for (int j = 0; j < 8; ++j) {
            const int o = xoff(pxs + j, icb) + icl;   // even
            *reinterpret_cast<u32*>(&xs[o]) = pack2h(e0[j], e1[j]);
        }
    }
    __syncthreads();

    const int lane = tid & 63;
    const int wv = tid >> 6;
    const int oc0 = (wv >> 1) * 48;
    const int pxw = (wv & 1) * 64;
    const int lr = lane & 15, lg = lane >> 4;

    const int npass = (sec == 0) ? 1 : 2;
    #pragma unroll 1
    for (int kvs = 0; kvs < npass; ++kvs) {
        const u16* wh = wf + ((sec == 0) ? 0 : (96 + kvs * 96)) * 96;
        u16* dst = (sec == 0) ? (qpre + (size_t)b * 96 * HWn)
                              : (kvpre + (size_t)b * 192 * HWn + (size_t)kvs * 96 * HWn);

        f32x4 acc[3][4];
        #pragma unroll
        for (int m = 0; m < 3; ++m)
            #pragma unroll
            for (int n = 0; n < 4; ++n)
                acc[m][n] = (f32x4){0.f, 0.f, 0.f, 0.f};

        #pragma unroll 1
        for (int kt = 0; kt < 3; ++kt) {
            const int kb = kt * 32;
            f16x8 B[4];
            #pragma unroll
            for (int n = 0; n < 4; ++n)
                B[n] = *(const f16x8*)(xs + xoff(pxw + n * 16 + lr, (kb >> 3) + lg));
            f16x8 A[3];
            #pragma unroll
            for (int m = 0; m < 3; ++m)
                A[m] = *(const f16x8*)(wh + (oc0 + m * 16 + lr) * 96 + kb + lg * 8);
            #pragma unroll
            for (int m = 0; m < 3; ++m)
                #pragma unroll
                for (int n = 0; n < 4; ++n)
                    acc[m][n] = __builtin_amdgcn_mfma_f32_16x16x32_f16(A[m], B[n], acc[m][n], 0, 0, 0);
        }

        #pragma unroll
        for (int m = 0; m < 3; ++m) {
            #pragma unroll
            for (int i = 0; i < 4; ++i) {
                const int oc = oc0 + m * 16 + lg * 4 + i;
                u16* drow = dst + (size_t)oc * HWn + px0;
                #pragma unroll
                for (int n = 0; n < 4; ++n)
                    drow[pxw + n * 16 + lr] = f2h(acc[m][n][i]);
            }
        }
    }
}

// K2: fused depthwise 3x3 + reductions. 128-px half-row tiles, 512 thr,
// LDS 52 KB. Horizontal halo via __shfl; S via f16 MFMA. All planes f16.
__global__ __launch_bounds__(512) void k_dw_fused(
    const u16* __restrict__ qpre, const u16* __restrict__ kvpre,
    const float* __restrict__ wqdw, const float* __restrict__ wkvdw,
    u16* __restrict__ vout, float* __restrict__ ssq, float* __restrict__ Sg)
{
    const int bid = blockIdx.x;                  // 0..2047
    const int wg = (bid & 7) * 256 + (bid >> 3); // XCD: contiguous y span per XCD
    const int b = wg >> 9;
    const int rem = wg & 511;
    const int y = rem >> 1;
    const int tx = (rem & 1) * 128;
    const int tid = threadIdx.x;
    const int lane = tid & 63;
    const int chunk = tid & 15;
    const int x0l = chunk * 8;
    const int xg = tx + x0l;

    __shared__ __align__(16) u16 qs[96][136];
    __shared__ __align__(16) u16 ks[96][136];

    #pragma unroll 1
    for (int it = 0; it < 9; ++it) {
        const int p = it * 32 + (tid >> 4);      // plane 0..287
        const u16* src; const float* wp; int c;
        if (p < 96)       { c = p;       src = qpre  + ((size_t)(b * 96 + c)) * HWn;       wp = wqdw  + c * 9; }
        else if (p < 192) { c = p - 96;  src = kvpre + ((size_t)(b * 192 + c)) * HWn;      wp = wkvdw + c * 9; }
        else              { c = p - 192; src = kvpre + ((size_t)(b * 192 + 96 + c)) * HWn; wp = wkvdw + (96 + c) * 9; }

        float a0 = 0.f, a1 = 0.f, a2 = 0.f, a3 = 0.f, a4 = 0.f, a5 = 0.f, a6 = 0.f, a7 = 0.f;

        #pragma unroll
        for (int r = 0; r < 3; ++r) {
            const int ry = y + r - 1;
            if ((unsigned)ry < 256u) {
                const u16* row = src + ry * 256 + xg;
                const uint4 m = *reinterpret_cast<const uint4*>(row);
                const float v1 = hlo(m.x), v2 = hhi(m.x);
                const float v3 = hlo(m.y), v4 = hhi(m.y);
                const float v5 = hlo(m.z), v6 = hhi(m.z);
                const float v7 = hlo(m.w), v8 = hhi(m.w);
                const float lv = __shfl(v8, (lane - 1) & 63);
                const float rv = __shfl(v1, (lane + 1) & 63);
                const float v0 = (chunk == 0)  ? ((xg > 0)       ? h2f(row[-1]) : 0.f) : lv;
                const float v9 = (chunk == 15) ? ((xg + 8 < 256) ? h2f(row[8])  : 0.f) : rv;
                const float w0 = wp[r * 3 + 0], w1 = wp[r * 3 + 1], w2 = wp[r * 3 + 2];
                a0 = fmaf(w0, v0, fmaf(w1, v1, fmaf(w2, v2, a0)));
                a1 = fmaf(w0, v1, fmaf(w1, v2, fmaf(w2, v3, a1)));
                a2 = fmaf(w0, v2, fmaf(w1, v3, fmaf(w2, v4, a2)));
                a3 = fmaf(w0, v3, fmaf(w1, v4, fmaf(w2, v5, a3)));
                a4 = fmaf(w0, v4, fmaf(w1, v5, fmaf(w2, v6, a4)));
                a5 = fmaf(w0, v5, fmaf(w1, v6, fmaf(w2, v7, a5)));
                a6 = fmaf(w0, v6, fmaf(w1, v7, fmaf(w2, v8, a6)));
                a7 = fmaf(w0, v7, fmaf(w1, v8, fmaf(w2, v9, a7)));
            }
        }

        const uint4 o = make_uint4(pack2h(a0, a1), pack2h(a2, a3), pack2h(a4, a5), pack2h(a6, a7));
        if (p < 96) {
            *reinterpret_cast<uint4*>(&qs[c][x0l]) = o;
        } else if (p < 192) {
            *reinterpret_cast<uint4*>(&ks[c][x0l]) = o;
        } else {
            *reinterpret_cast<uint4*>(vout + ((size_t)(b * 96 + c)) * HWn + y * 256 + xg) = o;
        }
    }
    __syncthreads();

    // ssq: 192 rows x 2 halves (64 px) = 384 tasks
    if (tid < 384) {
        const int half = tid >= 192;
        const int r = tid - half * 192;
        const uint4* rr = reinterpret_cast<const uint4*>(
            (r < 96 ? &qs[r][0] : &ks[r - 96][0]) + half * 64);
        float s = 0.f;
        #pragma unroll
        for (int pch = 0; pch < 8; ++pch) {
            const uint4 a = rr[pch];
            s += sq2h(a.x) + sq2h(a.y) + sq2h(a.z) + sq2h(a.w);
        }
        atomicAdd(ssq + b * 192 + r, s);
    }

    // S via f16 MFMA: wave w -> head h = w&3, row-tile mt = w>>2.
    {
        const int w = tid >> 6;
        const int h = w & 3, mt = w >> 2;
        const int lr2 = lane & 15, lg2 = lane >> 4;
        const int ar = h * 24 + min(mt * 16 + lr2, 23);  // clamp-dup, discard on store
        f32x4 acc2[2];
        acc2[0] = (f32x4){0.f, 0.f, 0.f, 0.f};
        acc2[1] = (f32x4){0.f, 0.f, 0.f, 0.f};
        #pragma unroll
        for (int ks4 = 0; ks4 < 4; ++ks4) {
            const f16x8 A = *(const f16x8*)(&qs[ar][ks4 * 32 + lg2 * 8]);
            #pragma unroll
            for (int nt = 0; nt < 2; ++nt) {
                const int bc = h * 24 + min(nt * 16 + lr2, 23);
                const f16x8 B = *(const f16x8*)(&ks[bc][ks4 * 32 + lg2 * 8]);
                acc2[nt] = __builtin_amdgcn_mfma_f32_16x16x32_f16(A, B, acc2[nt], 0, 0, 0);
            }
        }
        #pragma unroll
        for (int nt = 0; nt < 2; ++nt) {
            const int col = nt * 16 + lr2;
            #pragma unroll
            for (int reg = 0; reg < 4; ++reg) {
                const int row24 = mt * 16 + lg2 * 4 + reg;
                if (row24 < 24 && col < 24)
                    atomicAdd(Sg + b * 2304 + h * 576 + row24 * 24 + col, acc2[nt][reg]);
            }
        }
    }
}

// K3: normalize, softmax, fold w_out with block-diag attn -> Mf [oc][dg] f16
__global__ __launch_bounds__(256) void k_attn_fold(
    const float* __restrict__ ssq, const float* __restrict__ S,
    const float* __restrict__ temp, const float* __restrict__ w_out,
    u16* __restrict__ mf)
{
    const int b = blockIdx.x;
    const int tid = threadIdx.x;
    __shared__ float rq[96], rk[96], att[2304];

    if (tid < 96) {
        rq[tid] = 1.f / fmaxf(sqrtf(ssq[b * 192 + tid]), 1e-12f);
    } else if (tid < 192) {
        const int c = tid - 96;
        rk[c] = 1.f / fmaxf(sqrtf(ssq[b * 192 + 96 + c]), 1e-12f);
    }
    __syncthreads();

    if (tid < 96) {
        const int h = tid / 24, i = tid % 24;
        const float tmp = temp[h];
        const float rqi = rq[h * 24 + i];
        float l[24];
        float m = -1e30f;
        #pragma unroll
        for (int j = 0; j < 24; ++j) {
            l[j] = S[b * 2304 + (h * 24 + i) * 24 + j] * rqi * rk[h * 24 + j] * tmp;
            m = fmaxf(m, l[j]);
        }
        float ssum = 0.f;
        #pragma unroll
        for (int j = 0; j < 24; ++j) { l[j] = expf(l[j] - m); ssum += l[j]; }
        const float inv = 1.f / ssum;
        #pragma unroll
        for (int j = 0; j < 24; ++j) att[(h * 24 + i) * 24 + j] = l[j] * inv;
    }
    __syncthreads();

    for (int k = 0; k < 36; ++k) {
        const int id = k * 256 + tid;
        const int dg = id / 96, oc = id % 96;
        const int h = dg / 24, d24 = dg % 24;
        float s = 0.f;
        #pragma unroll
        for (int i = 0; i < 24; ++i) {
            s += w_out[oc * 96 + h * 24 + i] * att[(h * 24 + i) * 24 + d24];
        }
        mf[b * 9216 + oc * 96 + dg] = f2h(s);
    }
}

// K4: out = M @ v via f16 MFMA. grid (512 px-tiles, 4 b), 256 thr, 32 KB LDS.
__global__ __launch_bounds__(256, 5) void k_out_mfma(
    const u16* __restrict__ v, const u16* __restrict__ mf,
    float* __restrict__ out)
{
    const int b = blockIdx.y;
    const int px0 = blockIdx.x * 128;
    const int tid = threadIdx.x;
    __shared__ __align__(16) u16 xt[16384];

    const u16* vb = v + (size_t)b * 96 * HWn;
    const u16* mh = mf + b * 9216;

    const int icq = (tid >> 4) * 2;
    const int pxs = (tid & 15) * 8;
    #pragma unroll 1
    for (int p = 0; p < 3; ++p) {
        const int dg = p * 32 + icq;
        const uint4 u0 = *reinterpret_cast<const uint4*>(vb + (size_t)dg * HWn + px0 + pxs);
        const uint4 u1 = *reinterpret_cast<const uint4*>(vb + (size_t)(dg + 1) * HWn + px0 + pxs);
        const u32 w0[4] = {u0.x, u0.y, u0.z, u0.w};
        const u32 w1[4] = {u1.x, u1.y, u1.z, u1.w};
        const int icb = dg >> 3, icl = dg & 7;
        #pragma unroll
        for (int j = 0; j < 8; ++j) {
            const u32 lo = (w0[j >> 1] >> ((j & 1) * 16)) & 0xffffu;
            const u32 hi = (w1[j >> 1] >> ((j & 1) * 16)) & 0xffffu;
            const int o = xoff(pxs + j, icb) + icl;      // even
            *reinterpret_cast<u32*>(&xt[o]) = (hi << 16) | lo;
        }
    }
    __syncthreads();

    const int lane = tid & 63;
    const int wv = tid >> 6;
    const int oc0 = (wv >> 1) * 48;
    const int pxw = (wv & 1) * 64;
    const int lr = lane & 15, lg = lane >> 4;

    f32x4 acc[3][4];
    #pragma unroll
    for (int m = 0; m < 3; ++m)
        #pragma unroll
        for (int n = 0; n < 4; ++n)
            acc[m][n] = (f32x4){0.f, 0.f, 0.f, 0.f};

    #pragma unroll 1
    for (int kt = 0; kt < 3; ++kt) {
        const int kb = kt * 32;
        f16x8 B[4];
        #pragma unroll
        for (int n = 0; n < 4; ++n)
            B[n] = *(const f16x8*)(xt + xoff(pxw + n * 16 + lr, (kb >> 3) + lg));
        f16x8 A[3];
        #pragma unroll
        for (int m = 0; m < 3; ++m)
            A[m] = *(const f16x8*)(mh + (oc0 + m * 16 + lr) * 96 + kb + lg * 8);
        #pragma unroll
        for (int m = 0; m < 3; ++m)
            #pragma unroll
            for (int n = 0; n < 4; ++n)
                acc[m][n] = __builtin_amdgcn_mfma_f32_16x16x32_f16(A[m], B[n], acc[m][n], 0, 0, 0);
    }

    #pragma unroll
    for (int m = 0; m < 3; ++m) {
        #pragma unroll
        for (int i = 0; i < 4; ++i) {
            const int oc = oc0 + m * 16 + lg * 4 + i;
            float* drow = out + ((size_t)(b * 96 + oc)) * HWn + px0;
            #pragma unroll
            for (int n = 0; n < 4; ++n)
                drow[pxw + n * 16 + lr] = acc[m][n][i];
        }
    }
}

extern "C" void kernel_launch(void* const* d_in, const int* in_sizes, int n_in,
                              void* d_out, int out_size, void* d_ws, size_t ws_size,
                              hipStream_t stream) {
    (void)in_sizes; (void)n_in; (void)out_size; (void)ws_size;
    const float* x      = (const float*)d_in[0];
    const float* ff     = (const float*)d_in[1];
    const float* w_q    = (const float*)d_in[2];
    const float* w_kv   = (const float*)d_in[3];
    const float* w_q_dw = (const float*)d_in[4];
    const float* w_kv_dw= (const float*)d_in[5];
    const float* w_out  = (const float*)d_in[6];
    const float* temp   = (const float*)d_in[7];
    float* out = (float*)d_out;

    char* ws = (char*)d_ws;
    u16* qpre   = (u16*)(ws);                      //  50,331,648 B
    u16* kvpre  = (u16*)(ws + 50331648);           // 100,663,296 B
    u16* vbuf   = (u16*)(ws + 150994944);          //  50,331,648 B
    float* ssq  = (float*)(ws + 201326592);        //       3,072 B
    float* S    = (float*)(ws + 201329664);        //      36,864 B
    u16* wf     = (u16*)(ws + 201366528);          //      55,296 B
    u16* mf     = (u16*)(ws + 201421824);          //      73,728 B

    hipMemsetAsync(ssq, 0, 3072 + 36864, stream);

    k_prep_w<<<108, 256, 0, stream>>>(w_q, w_kv, wf);
    k_conv_mfma<<<dim3(512, 2, 4), 256, 0, stream>>>(ff, x, wf, qpre, kvpre);
    k_dw_fused<<<dim3(2048), 512, 0, stream>>>(qpre, kvpre, w_q_dw, w_kv_dw, vbuf, ssq, S);
    k_attn_fold<<<4, 256, 0, stream>>>(ssq, S, temp, w_out, mf);
    k_out_mfma<<<dim3(512, 4), 256, 0, stream>>>(vbuf, mf, out);
}